// Round 1
// baseline (582.189 us; speedup 1.0000x reference)
//
#include <hip/hip_runtime.h>
#include <hip/hip_bf16.h>

// SamClip: N=1024 masks of 256x256 (binary fp32), scores[1024].
// Output (int32): d_out[0:1024] = order (argsort desc, stable), d_out[1024:2048] = keep (0/1).
//
// Strategy: bitpack masks (exact), inter = popcount(AND), per-column max reductions.

#define N_MASKS 1024
#define HW 65536          // 256*256 pixels
#define WPR 2048          // u32 words per packed row
#define STRIDE 68         // LDS row stride in words (272B: 16B-aligned, 2-way max bank alias)

// ---------------- Kernel A: stable descending argsort + init ----------------
__global__ __launch_bounds__(128) void sort_kernel(const float* __restrict__ scores,
                                                   int* __restrict__ order,
                                                   float* __restrict__ ssort,
                                                   int* __restrict__ out_order,
                                                   unsigned* __restrict__ ioumax,
                                                   unsigned* __restrict__ innu,
                                                   unsigned* __restrict__ innl) {
    __shared__ float s[N_MASKS];
    const int t = threadIdx.x;
    for (int k = t; k < N_MASKS; k += 128) s[k] = scores[k];
    __syncthreads();
    const int i = blockIdx.x * 128 + t;
    const float si = s[i];
    int rank = 0;
    #pragma unroll 8
    for (int j = 0; j < N_MASKS; ++j) {
        const float sj = s[j];
        rank += (int)((sj > si) || (sj == si && j < i));
    }
    order[rank] = i;
    ssort[rank] = si;
    out_order[rank] = i;   // output 0: order indices as int32
    // zero the reduction arrays (i is a unique global index in [0,1024))
    ioumax[i] = 0u; innu[i] = 0u; innl[i] = 0u;
}

// ---------------- Kernel B: bitpack in sorted order + area ----------------
// Pixel->bit mapping is a fixed permutation (identical for every row), which
// preserves popcount(AND) and popcount(row). Fully coalesced float4 loads.
__global__ __launch_bounds__(256) void pack_kernel(const float* __restrict__ masks,
                                                   const int* __restrict__ order,
                                                   unsigned* __restrict__ packed,
                                                   float* __restrict__ area) {
    const int r = blockIdx.x;
    const int src = order[r];
    const float4* __restrict__ row = (const float4*)(masks + (size_t)src * HW);
    const int t = threadIdx.x;
    const int lane = t & 63, w = t >> 6;      // 4 waves
    unsigned* __restrict__ prow = packed + (size_t)r * WPR;
    int cnt = 0;
    #pragma unroll
    for (int g = 0; g < 8; ++g) {             // each wave: 8 groups of 2048 pixels
        unsigned bits = 0u;
        const int base = w * 4096 + g * 512;  // float4 index
        #pragma unroll
        for (int k = 0; k < 8; ++k) {
            const float4 f = row[base + k * 64 + lane];
            unsigned nib = (unsigned)(f.x != 0.0f)
                         | ((unsigned)(f.y != 0.0f) << 1)
                         | ((unsigned)(f.z != 0.0f) << 2)
                         | ((unsigned)(f.w != 0.0f) << 3);
            bits |= nib << (k * 4);
        }
        prow[w * 512 + g * 64 + lane] = bits;
        cnt += __builtin_popcount(bits);
    }
    // wave reduce then block reduce
    for (int off = 32; off > 0; off >>= 1) cnt += __shfl_down(cnt, off, 64);
    __shared__ int red[4];
    if (lane == 0) red[w] = cnt;
    __syncthreads();
    if (t == 0) area[r] = (float)(red[0] + red[1] + red[2] + red[3]);
}

// ---------------- Kernel C: pairwise popcount + column-max reductions ----------------
// Full 1024x1024 square as 16x16 blocks of 64x64 tiles (256 blocks = 1/CU).
// Entry (a,b): a = row i, b = col j of the sorted matrices.
//   a <  b   : contributes iou -> ioumax[b], inner(a,b) -> innu[b]
//   a >= b-1 : contributes inner(a,b) -> innl[b]
__global__ __launch_bounds__(256) void pair_kernel(const unsigned* __restrict__ packed,
                                                   const float* __restrict__ area,
                                                   unsigned* __restrict__ ioumax,
                                                   unsigned* __restrict__ innu,
                                                   unsigned* __restrict__ innl) {
    __shared__ __align__(16) unsigned lA[64 * STRIDE];
    __shared__ __align__(16) unsigned lB[64 * STRIDE];
    __shared__ unsigned redI[64], redU[64], redL[64];

    const int t = threadIdx.x;
    const int J = blockIdx.x, I = blockIdx.y;
    const int A0 = I * 64, B0 = J * 64;
    const int tx = t & 15, ty = t >> 4;       // 16x16 threads, 4x4 tile each

    unsigned acc[4][4] = {};

    for (int c = 0; c < WPR / 64; ++c) {      // 32 chunks of 64 words
        __syncthreads();
        // stage 64 rows x 64 words per side (uint4 per thread per rep)
        #pragma unroll
        for (int rep = 0; rep < 4; ++rep) {
            const int linear = rep * 1024 + t * 4;
            const int row = linear >> 6, col = linear & 63;
            const uint4 va = *(const uint4*)(packed + (size_t)(A0 + row) * WPR + c * 64 + col);
            const uint4 vb = *(const uint4*)(packed + (size_t)(B0 + row) * WPR + c * 64 + col);
            *(uint4*)(lA + row * STRIDE + col) = va;
            *(uint4*)(lB + row * STRIDE + col) = vb;
        }
        __syncthreads();
        #pragma unroll
        for (int g = 0; g < 16; ++g) {        // 16 k-groups of 4 words (b128)
            uint4 a[4], b[4];
            #pragma unroll
            for (int i = 0; i < 4; ++i)
                a[i] = *(const uint4*)(lA + (ty * 4 + i) * STRIDE + g * 4);
            #pragma unroll
            for (int j = 0; j < 4; ++j)
                b[j] = *(const uint4*)(lB + (tx * 4 + j) * STRIDE + g * 4);
            #pragma unroll
            for (int i = 0; i < 4; ++i)
                #pragma unroll
                for (int j = 0; j < 4; ++j) {
                    acc[i][j] += __builtin_popcount(a[i].x & b[j].x);
                    acc[i][j] += __builtin_popcount(a[i].y & b[j].y);
                    acc[i][j] += __builtin_popcount(a[i].z & b[j].z);
                    acc[i][j] += __builtin_popcount(a[i].w & b[j].w);
                }
        }
    }

    if (t < 64) { redI[t] = 0u; redU[t] = 0u; redL[t] = 0u; }
    __syncthreads();

    float aa[4], ab[4];
    #pragma unroll
    for (int i = 0; i < 4; ++i) aa[i] = area[A0 + ty * 4 + i];
    #pragma unroll
    for (int j = 0; j < 4; ++j) ab[j] = area[B0 + tx * 4 + j];

    #pragma unroll
    for (int i = 0; i < 4; ++i) {
        const int ga = A0 + ty * 4 + i;
        #pragma unroll
        for (int j = 0; j < 4; ++j) {
            const int gb = B0 + tx * 4 + j;
            const int lb = tx * 4 + j;
            const float inter = (float)acc[i][j];
            const float uni = aa[i] + ab[j] - inter;
            const float iou = inter / (uni + 1e-8f);
            const float ra = inter / (aa[i] + 1e-8f);   // ratio_i (row)
            const float rb = inter / (ab[j] + 1e-8f);   // ratio_j (col)
            // keep mul+sub unfused to match the reference's f32 arithmetic
            const float v = __fsub_rn(1.0f, __fmul_rn(ra, rb));
            const float innv = (ra < 0.5f && rb >= 0.85f) ? v : 0.0f;
            if (ga < gb) {
                atomicMax(&redI[lb], __float_as_uint(iou));
                atomicMax(&redU[lb], __float_as_uint(innv));
            }
            if (ga >= gb - 1) {
                atomicMax(&redL[lb], __float_as_uint(innv));
            }
        }
    }
    __syncthreads();
    if (t < 64) {
        atomicMax(&ioumax[B0 + t], redI[t]);
        atomicMax(&innu[B0 + t], redU[t]);
        atomicMax(&innl[B0 + t], redL[t]);
    }
}

// ---------------- Kernel D: final keep ----------------
__global__ __launch_bounds__(256) void keep_kernel(const float* __restrict__ ssort,
                                                   const unsigned* __restrict__ ioumax,
                                                   const unsigned* __restrict__ innu,
                                                   const unsigned* __restrict__ innl,
                                                   int* __restrict__ out_keep) {
    const int r = blockIdx.x * 256 + threadIdx.x;
    const float s0 = ssort[0];                 // max score (sorted desc)
    const bool conf = (s0 > 0.7f) ? (ssort[r] > 0.7f) : (r < 3);
    const bool keep = (__uint_as_float(ioumax[r]) <= 0.8f) && conf &&
                      (__uint_as_float(innu[r]) <= 0.5f) &&
                      (__uint_as_float(innl[r]) <= 0.5f);
    out_keep[r] = keep ? 1 : 0;
}

extern "C" void kernel_launch(void* const* d_in, const int* in_sizes, int n_in,
                              void* d_out, int out_size, void* d_ws, size_t ws_size,
                              hipStream_t stream) {
    const float* masks  = (const float*)d_in[0];
    const float* scores = (const float*)d_in[1];
    int* out = (int*)d_out;

    // workspace layout
    unsigned* packed = (unsigned*)d_ws;                       // 1024*2048 u32 = 8 MB
    int*      order  = (int*)(packed + (size_t)N_MASKS * WPR);
    float*    ssort  = (float*)(order + N_MASKS);
    float*    area   = (float*)(ssort + N_MASKS);
    unsigned* ioumax = (unsigned*)(area + N_MASKS);
    unsigned* innu   = ioumax + N_MASKS;
    unsigned* innl   = innu + N_MASKS;

    sort_kernel<<<8, 128, 0, stream>>>(scores, order, ssort, out, ioumax, innu, innl);
    pack_kernel<<<N_MASKS, 256, 0, stream>>>(masks, order, packed, area);
    dim3 grid(16, 16);
    pair_kernel<<<grid, 256, 0, stream>>>(packed, area, ioumax, innu, innl);
    keep_kernel<<<4, 256, 0, stream>>>(ssort, ioumax, innu, innl, out + N_MASKS);
}

// Round 2
// 503.272 us; speedup vs baseline: 1.1568x; 1.1568x over previous
//
#include <hip/hip_runtime.h>

// SamClip: N=1024 binary masks (256x256 fp32), scores[1024].
// out int32: [0:1024] = order (argsort desc, stable), [1024:2048] = keep (0/1).
//
// R2: bitpack + popcount pairwise, triangular 64x64 tiles, k-split x4,
// XOR-swizzled LDS (conflict-free b128 fragment reads), separate combine pass.

#define N_MASKS 1024
#define HW 65536
#define WPR 2048          // u32 words per packed row
#define NT 16             // 16x16 grid of 64-row tiles
#define NPAIRS 136        // NT*(NT+1)/2 triangular tile pairs
#define KQ 4              // k-split factor (each block does 512 words)

__device__ __forceinline__ void tile_from_pair(int p, int& I, int& J) {
    int rem = p, i = 0;
    while (rem >= NT - i) { rem -= NT - i; ++i; }
    I = i; J = i + rem;
}

// ---------------- Kernel A: stable descending argsort + init ----------------
__global__ __launch_bounds__(128) void sort_kernel(const float* __restrict__ scores,
                                                   int* __restrict__ order,
                                                   float* __restrict__ ssort,
                                                   int* __restrict__ out_order,
                                                   float* __restrict__ area,
                                                   unsigned* __restrict__ ioumax,
                                                   unsigned* __restrict__ innu,
                                                   unsigned* __restrict__ innl) {
    __shared__ float s[N_MASKS];
    const int t = threadIdx.x;
    for (int k = t; k < N_MASKS; k += 128) s[k] = scores[k];
    __syncthreads();
    const int i = blockIdx.x * 128 + t;
    const float si = s[i];
    int rank = 0;
    #pragma unroll 8
    for (int j = 0; j < N_MASKS; ++j) {
        const float sj = s[j];
        rank += (int)((sj > si) || (sj == si && j < i));
    }
    order[rank] = i;
    ssort[rank] = si;
    out_order[rank] = i;
    area[i] = 0.0f;
    ioumax[i] = 0u; innu[i] = 0u; innl[i] = 0u;
}

// ---------------- Kernel B: bitpack (sorted order) + area ----------------
// 2 blocks per mask row (half-row each). Fixed pixel->bit permutation,
// identical across rows, so popcounts are preserved exactly.
__global__ __launch_bounds__(256) void pack_kernel(const float* __restrict__ masks,
                                                   const int* __restrict__ order,
                                                   unsigned* __restrict__ packed,
                                                   float* __restrict__ area) {
    const int b = blockIdx.x;
    const int r = b >> 1, half = b & 1;
    const int src = order[r];
    const float4* __restrict__ row = (const float4*)(masks + (size_t)src * HW) + half * 8192;
    unsigned* __restrict__ prow = packed + (size_t)r * WPR + half * 1024;
    const int t = threadIdx.x;
    int cnt = 0;
    #pragma unroll
    for (int g = 0; g < 4; ++g) {
        unsigned bits = 0u;
        #pragma unroll
        for (int k = 0; k < 8; ++k) {
            const float4 f = row[g * 2048 + k * 256 + t];
            unsigned nib = (unsigned)(f.x != 0.0f)
                         | ((unsigned)(f.y != 0.0f) << 1)
                         | ((unsigned)(f.z != 0.0f) << 2)
                         | ((unsigned)(f.w != 0.0f) << 3);
            bits |= nib << (k * 4);
        }
        prow[g * 256 + t] = bits;
        cnt += __builtin_popcount(bits);
    }
    for (int off = 32; off > 0; off >>= 1) cnt += __shfl_down(cnt, off, 64);
    __shared__ int red[4];
    const int lane = t & 63, w = t >> 6;
    if (lane == 0) red[w] = cnt;
    __syncthreads();
    if (t == 0) atomicAdd(area + r, (float)(red[0] + red[1] + red[2] + red[3]));
}

// ---------------- Kernel C: pairwise popcount partials ----------------
// Block (p, kq): triangular tile pair p (I<=J), k-quarter kq (512 words).
// LDS XOR swizzle: logical (row, chunk c of 4 words) stored at physical chunk
// c ^ (row>>2). Fragment reads: a-side broadcast, b-side 16 distinct chunks
// across tx -> 2 lanes/bank-group -> conflict-free.
__global__ __launch_bounds__(256, 2) void pair_kernel(const unsigned* __restrict__ packed,
                                                      unsigned* __restrict__ partial) {
    __shared__ __align__(16) unsigned lA[64 * 64];
    __shared__ __align__(16) unsigned lB[64 * 64];

    const int p = blockIdx.x, kq = blockIdx.y;
    int I, J; tile_from_pair(p, I, J);
    const int A0 = I * 64, B0 = J * 64;
    const int t = threadIdx.x;
    const int tx = t & 15, ty = t >> 4;

    unsigned acc[4][4] = {};

    const int c0 = kq * (WPR / 64 / KQ);            // 8 chunks of 64 words
    for (int c = c0; c < c0 + (WPR / 64 / KQ); ++c) {
        __syncthreads();
        #pragma unroll
        for (int rep = 0; rep < 4; ++rep) {
            const int linear = rep * 1024 + t * 4;
            const int row = linear >> 6, col = linear & 63;
            const int phys = row * 64 + (((col >> 2) ^ (row >> 2)) << 2);
            const uint4 va = *(const uint4*)(packed + (size_t)(A0 + row) * WPR + c * 64 + col);
            const uint4 vb = *(const uint4*)(packed + (size_t)(B0 + row) * WPR + c * 64 + col);
            *(uint4*)(lA + phys) = va;
            *(uint4*)(lB + phys) = vb;
        }
        __syncthreads();
        #pragma unroll
        for (int g = 0; g < 16; ++g) {
            uint4 a[4], b[4];
            #pragma unroll
            for (int i = 0; i < 4; ++i)
                a[i] = *(const uint4*)(lA + (ty * 4 + i) * 64 + ((g ^ ty) << 2));
            #pragma unroll
            for (int j = 0; j < 4; ++j)
                b[j] = *(const uint4*)(lB + (tx * 4 + j) * 64 + ((g ^ tx) << 2));
            #pragma unroll
            for (int i = 0; i < 4; ++i)
                #pragma unroll
                for (int j = 0; j < 4; ++j) {
                    acc[i][j] += __builtin_popcount(a[i].x & b[j].x);
                    acc[i][j] += __builtin_popcount(a[i].y & b[j].y);
                    acc[i][j] += __builtin_popcount(a[i].z & b[j].z);
                    acc[i][j] += __builtin_popcount(a[i].w & b[j].w);
                }
        }
    }

    unsigned* __restrict__ out = partial + ((size_t)kq * NPAIRS + p) * 4096;
    #pragma unroll
    for (int i = 0; i < 4; ++i) {
        uint4 v = make_uint4(acc[i][0], acc[i][1], acc[i][2], acc[i][3]);
        *(uint4*)(out + (ty * 4 + i) * 64 + tx * 4) = v;
    }
}

// ---------------- Kernel D: combine partials + epilogue + column max ----------------
__global__ __launch_bounds__(256) void combine_kernel(const unsigned* __restrict__ partial,
                                                      const float* __restrict__ area,
                                                      unsigned* __restrict__ ioumax,
                                                      unsigned* __restrict__ innu,
                                                      unsigned* __restrict__ innl) {
    __shared__ float aA[64], aB[64];
    __shared__ unsigned redI[64], redU[64], redLA[64], redLB[64];

    const int p = blockIdx.x;
    int I, J; tile_from_pair(p, I, J);
    const int A0 = I * 64, B0 = J * 64;
    const int t = threadIdx.x;
    if (t < 64) {
        aA[t] = area[A0 + t]; aB[t] = area[B0 + t];
        redI[t] = 0u; redU[t] = 0u; redLA[t] = 0u; redLB[t] = 0u;
    }
    __syncthreads();

    const int tx = t & 15, ty = t >> 4;
    float mI[4] = {0,0,0,0}, mU[4] = {0,0,0,0}, mLB[4] = {0,0,0,0}, mLA[4] = {0,0,0,0};

    #pragma unroll
    for (int i = 0; i < 4; ++i) {
        const int arow = ty * 4 + i;
        const int a = A0 + arow;
        const size_t off = (size_t)p * 4096 + arow * 64 + tx * 4;
        const uint4 s0 = *(const uint4*)(partial + 0u * NPAIRS * 4096 + off);
        const uint4 s1 = *(const uint4*)(partial + 1u * NPAIRS * 4096 + off);
        const uint4 s2 = *(const uint4*)(partial + 2u * NPAIRS * 4096 + off);
        const uint4 s3 = *(const uint4*)(partial + 3u * NPAIRS * 4096 + off);
        unsigned sums[4] = { s0.x + s1.x + s2.x + s3.x, s0.y + s1.y + s2.y + s3.y,
                             s0.z + s1.z + s2.z + s3.z, s0.w + s1.w + s2.w + s3.w };
        const float fa = aA[arow];
        #pragma unroll
        for (int j = 0; j < 4; ++j) {
            const int b = B0 + tx * 4 + j;
            if (a > b) continue;
            const float inter = (float)sums[j];
            const float fb = aB[tx * 4 + j];
            const float uni = (fb + fa) - inter;             // ref: area_j + area_i - inter
            const float iou = inter / (uni + 1e-8f);
            const float ra = inter / (fa + 1e-8f);           // ratio_i (row a)
            const float rb = inter / (fb + 1e-8f);           // ratio_j (col b)
            const float v = __fsub_rn(1.0f, __fmul_rn(rb, ra));
            const float iab = (ra < 0.5f && rb >= 0.85f) ? v : 0.0f;
            const float iba = (rb < 0.5f && ra >= 0.85f) ? v : 0.0f;
            if (a < b) {
                mI[j] = fmaxf(mI[j], iou);
                mU[j] = fmaxf(mU[j], iab);    // inner[a,b], a<b  -> innu[b]
                mLA[i] = fmaxf(mLA[i], iba);  // inner[b,a], b>=a-1 -> innl[a]
            }
            if (a == b - 1) mLB[j] = fmaxf(mLB[j], iab);      // superdiag -> innl[b]
        }
    }
    #pragma unroll
    for (int j = 0; j < 4; ++j) {
        atomicMax(&redI[tx * 4 + j], __float_as_uint(mI[j]));
        atomicMax(&redU[tx * 4 + j], __float_as_uint(mU[j]));
        atomicMax(&redLB[tx * 4 + j], __float_as_uint(mLB[j]));
    }
    #pragma unroll
    for (int i = 0; i < 4; ++i)
        atomicMax(&redLA[ty * 4 + i], __float_as_uint(mLA[i]));
    __syncthreads();
    if (t < 64) {
        atomicMax(&ioumax[B0 + t], redI[t]);
        atomicMax(&innu[B0 + t], redU[t]);
        atomicMax(&innl[B0 + t], redLB[t]);
        atomicMax(&innl[A0 + t], redLA[t]);
    }
}

// ---------------- Kernel E: final keep ----------------
__global__ __launch_bounds__(256) void keep_kernel(const float* __restrict__ ssort,
                                                   const unsigned* __restrict__ ioumax,
                                                   const unsigned* __restrict__ innu,
                                                   const unsigned* __restrict__ innl,
                                                   int* __restrict__ out_keep) {
    const int r = blockIdx.x * 256 + threadIdx.x;
    const float s0 = ssort[0];
    const bool conf = (s0 > 0.7f) ? (ssort[r] > 0.7f) : (r < 3);
    const bool keep = (__uint_as_float(ioumax[r]) <= 0.8f) && conf &&
                      (__uint_as_float(innu[r]) <= 0.5f) &&
                      (__uint_as_float(innl[r]) <= 0.5f);
    out_keep[r] = keep ? 1 : 0;
}

extern "C" void kernel_launch(void* const* d_in, const int* in_sizes, int n_in,
                              void* d_out, int out_size, void* d_ws, size_t ws_size,
                              hipStream_t stream) {
    const float* masks  = (const float*)d_in[0];
    const float* scores = (const float*)d_in[1];
    int* out = (int*)d_out;

    unsigned* packed  = (unsigned*)d_ws;                       // 8 MB
    unsigned* partial = packed + (size_t)N_MASKS * WPR;        // 4*136*4096 u32 = 8.5 MB
    unsigned* tail    = partial + (size_t)KQ * NPAIRS * 4096;
    int*      order   = (int*)tail;
    float*    ssort   = (float*)(order + N_MASKS);
    float*    area    = (float*)(ssort + N_MASKS);
    unsigned* ioumax  = (unsigned*)(area + N_MASKS);
    unsigned* innu    = ioumax + N_MASKS;
    unsigned* innl    = innu + N_MASKS;

    sort_kernel<<<8, 128, 0, stream>>>(scores, order, ssort, out, area, ioumax, innu, innl);
    pack_kernel<<<2048, 256, 0, stream>>>(masks, order, packed, area);
    pair_kernel<<<dim3(NPAIRS, KQ), 256, 0, stream>>>(packed, partial);
    combine_kernel<<<NPAIRS, 256, 0, stream>>>(partial, area, ioumax, innu, innl);
    keep_kernel<<<4, 256, 0, stream>>>(ssort, ioumax, innu, innl, out + N_MASKS);
}